// Round 9
// baseline (1311.177 us; speedup 1.0000x reference)
//
#include <hip/hip_runtime.h>
#include <hip/hip_bf16.h>

// Problem dims
#define BB 64
#define TT 168
#define NN 64
#define FF 17
#define HID 128
#define GATES 512   // 4*HID
#define NLAYERS 4
#define NROWS (BB*TT)   // 10752

// LSTM pipeline chunking
#define CH 8
#define NCHUNK (TT/CH)  // 21

// Workspace layout (float offsets)
#define WS_W1SRC 0
#define WS_W1DST 32
#define WS_W2SRC 64
#define WS_W2DST 192
#define WS_BSUM  320                    // 4*512 -> ends 2368
#define WS_WD    2560                   // 17 (pad 32): W1 @ (W2 @ a2dst)
#define WS_WSV   2592                   // 17 (pad 32): W1 @ (W2 @ a2src)
#define WS_W12   2624                   // 17*128 = 2176: W1 @ W2
#define WS_WXG0T 4800                   // 512*20 (17 used): (W12 @ Wih0^T)^T rows -> ends 15040
#define WS_ADJB  15104                  // 64 u64 adjacency bitmasks (128 floats) -> ends 15232
#define WS_FLAGS 16000                  // 256 ints: per-(layer,batch) progress counters
#define WS_XG    1395712                // NROWS*512 = 5505024 (layer-0 gates from GAT)
#define WS_HSEQ0 6900736                // 4 buffers of NROWS*HID
#define HSEQ_SZ  1376256

// LDS-only barrier: s_waitcnt lgkmcnt(0) + raw s_barrier (no vmcnt drain).
__device__ __forceinline__ void lds_barrier() {
    __asm__ volatile("" ::: "memory");
    __builtin_amdgcn_s_waitcnt(0xc07f);
    __builtin_amdgcn_s_barrier();
    __asm__ volatile("" ::: "memory");
}

__device__ __forceinline__ float fsig(float x) {
    return __builtin_amdgcn_rcpf(1.f + __expf(-x));
}
__device__ __forceinline__ float ftanh(float x) {
    float e = __expf(2.f * x);
    return 1.f - 2.f * __builtin_amdgcn_rcpf(e + 1.f);
}
__device__ __forceinline__ float bcast_lane(float v, int lane) {
    return __int_as_float(__builtin_amdgcn_readlane(__float_as_int(v), lane));
}

// ---------------- prep1: attention projection vectors + bias sums + adj bitmasks + flag reset ----------------
__global__ void prep1(const float* __restrict__ W1, const float* __restrict__ a1,
                      const float* __restrict__ W2, const float* __restrict__ a2,
                      const float* __restrict__ bih, const float* __restrict__ bhh,
                      const int* __restrict__ adj, float* __restrict__ ws) {
    int tid = threadIdx.x;
    if (tid < 34) {
        int f = tid % FF, half = tid / FF;
        float acc = 0.f;
        for (int o = 0; o < HID; o++) acc += W1[f*HID + o] * a1[half*HID + o];
        ws[(half ? WS_W1DST : WS_W1SRC) + f] = acc;
    }
    {
        int k = tid & 127, half = tid >> 7;
        float acc = 0.f;
        for (int o = 0; o < HID; o++) acc += W2[k*HID + o] * a2[half*HID + o];
        ws[(half ? WS_W2DST : WS_W2SRC) + k] = acc;
    }
    for (int idx = tid; idx < NLAYERS*GATES; idx += 256) ws[WS_BSUM + idx] = bih[idx] + bhh[idx];
    // adjacency bitmasks (with self-loop), computed once for all 10752 GAT blocks
    if (tid < 64) {
        unsigned long long m = 1ull << tid;
        const int* ar = adj + tid*64;
        for (int j = 0; j < 64; j++) if (ar[j] > 0) m |= (1ull << j);
        ((unsigned long long*)(ws + WS_ADJB))[tid] = m;
    }
    // reset pipeline flags (agent-scope so lstm_pipe's coherent loads see zeros)
    __hip_atomic_store((int*)(ws + WS_FLAGS) + tid, 0,
                       __ATOMIC_RELAXED, __HIP_MEMORY_SCOPE_AGENT);
}

// ---------------- prep2: W12 = W1 @ W2 (17 x 128) ----------------
__global__ void prep2(const float* __restrict__ W1, const float* __restrict__ W2,
                      float* __restrict__ ws) {
    int f = blockIdx.x, o = threadIdx.x;
    float acc = 0.f;
    for (int k = 0; k < HID; k++) acc += W1[f*HID + k] * W2[k*HID + o];
    ws[WS_W12 + f*HID + o] = acc;
}

// ---------------- prep3: WD/WSV (17 each) + WXG0T (512 x 17, stride 20) ----------------
__global__ void prep3(const float* __restrict__ W1, const float* __restrict__ Wih0,
                      float* __restrict__ ws) {
    int idx = blockIdx.x * 256 + threadIdx.x;
    if (idx < 17) {
        int f = idx;
        float acc = 0.f;
        for (int k = 0; k < HID; k++) acc += W1[f*HID + k] * ws[WS_W2DST + k];
        ws[WS_WD + f] = acc;
    } else if (idx < 34) {
        int f = idx - 17;
        float acc = 0.f;
        for (int k = 0; k < HID; k++) acc += W1[f*HID + k] * ws[WS_W2SRC + k];
        ws[WS_WSV + f] = acc;
    } else if (idx < 34 + GATES*FF) {
        int e = idx - 34;
        int j = e % GATES, f = e / GATES;   // f < 17
        float acc = 0.f;
        for (int o = 0; o < HID; o++) acc += ws[WS_W12 + f*HID + o] * Wih0[j*HID + o];
        ws[WS_WXG0T + j*20 + f] = acc;
    }
}

// ---------------- K1: fused GAT1 + GAT2(site) -> Xg layer-0 directly ----------------
struct __align__(16) GatSmem {
    float attn[64*68];       // P2 writes rows (stride 68), P3 reads
    float xsT[FF*64];        // [f][n]
    float xbarT[FF*68];      // [f][i], stride 68
    float src1[64], dst1[64], rinv[64], att2[64];
    float xbar2[20];
    float part_x[FF*8];      // P5a partials
    unsigned long long adjbits[64];
};
// ~28.5 KB -> 5 blocks/CU

__global__ __launch_bounds__(256) void gat_fused(const float* __restrict__ x, const int* __restrict__ adj,
                                                 const float* __restrict__ ws,
                                                 float* __restrict__ Xg, const int* __restrict__ site_ptr) {
    __shared__ GatSmem sm;
    const int tid = threadIdx.x;
    const int tt = blockIdx.x, bb = blockIdx.y;
    const int site = site_ptr[0];
    const int r = bb*TT + tt;
    const float* xblk = x + (size_t)r * (NN*FF);

    // P0: x transposed into LDS, adjacency bitmasks from prep1
    for (int idx = tid; idx < NN*FF; idx += 256) {
        int n = idx / FF, f = idx % FF;
        sm.xsT[f*64 + n] = xblk[idx];
    }
    if (tid < 64) sm.adjbits[tid] = ((const unsigned long long*)(ws + WS_ADJB))[tid];
    lds_barrier();

    // P1: src1/dst1 = x . (W1 @ a1-halves)
    if (tid < 128) {
        int n = tid & 63, half = tid >> 6;
        const float* wv = ws + (half ? WS_W1DST : WS_W1SRC);
        float acc = 0.f;
        #pragma unroll
        for (int f = 0; f < FF; f++) acc += sm.xsT[f*64 + n] * wv[f];
        if (half) sm.dst1[n] = acc; else sm.src1[n] = acc;
    }
    lds_barrier();

    // P2: attention logits -> exp -> attn rows
    {
        int q = tid & 3, i = tid >> 2;
        unsigned long long ab = sm.adjbits[i];
        float si = sm.src1[i];
        float v[16];
        float vmax = -1e30f;
        #pragma unroll
        for (int u = 0; u < 16; u++) {
            int jj = q*16 + u;
            float e = si + sm.dst1[jj];
            float lv = fmaxf(e, 0.2f*e);
            lv = ((ab >> jj) & 1ull) ? lv : -1e9f;
            v[u] = lv;
            vmax = fmaxf(vmax, lv);
        }
        vmax = fmaxf(vmax, __shfl_xor(vmax, 1, 4));
        vmax = fmaxf(vmax, __shfl_xor(vmax, 2, 4));
        float s = 0.f;
        float* arow = &sm.attn[i*68];
        #pragma unroll
        for (int w = 0; w < 4; w++) {
            float4 pv;
            pv.x = __expf(v[w*4+0] - vmax);
            pv.y = __expf(v[w*4+1] - vmax);
            pv.z = __expf(v[w*4+2] - vmax);
            pv.w = __expf(v[w*4+3] - vmax);
            s += (pv.x + pv.y) + (pv.z + pv.w);
            *(float4*)(arow + q*16 + w*4) = pv;
        }
        s += __shfl_xor(s, 1, 4);
        s += __shfl_xor(s, 2, 4);
        if (q == 0) sm.rinv[i] = 1.f / s;
    }
    lds_barrier();

    // P3: xbarT[f][i] = (P @ X)[i][f] * rinv
    {
        int i = tid & 63, q = tid >> 6;
        const float* arow = &sm.attn[i*68];
        float acc[5] = {0.f,0.f,0.f,0.f,0.f};
        const int nf = (q == 0) ? 5 : 4;
        for (int j4 = 0; j4 < 16; j4++) {
            float4 a4 = *(const float4*)(arow + j4*4);
            #pragma unroll
            for (int u = 0; u < 5; u++) {
                if (u < nf) {
                    int f = q + 4*u;
                    float4 x4 = *(const float4*)(&sm.xsT[f*64 + j4*4]);
                    acc[u] += a4.x*x4.x + a4.y*x4.y + a4.z*x4.z + a4.w*x4.w;
                }
            }
        }
        float ri = sm.rinv[i];
        #pragma unroll
        for (int u = 0; u < 5; u++) {
            if (u < nf) sm.xbarT[(q + 4*u)*68 + i] = acc[u] * ri;
        }
    }
    lds_barrier();

    // P4' (wave 0): dst2[j] = xbar[j].WD ; src2 = xbar[site].WSV ; softmax -> att2
    if (tid < 64) {
        int jj = tid;
        float d = 0.f, sp = 0.f;
        #pragma unroll
        for (int f = 0; f < FF; f++) {
            float xv = sm.xbarT[f*68 + jj];
            float xsv = sm.xbarT[f*68 + site];
            d  += xv * ws[WS_WD + f];
            sp += xsv * ws[WS_WSV + f];
        }
        unsigned long long ab = sm.adjbits[site];
        float e = sp + d;
        float lv = fmaxf(e, 0.2f*e);
        lv = ((ab >> jj) & 1ull) ? lv : -1e9f;
        float m = lv;
        #pragma unroll
        for (int dd = 1; dd < 64; dd <<= 1) m = fmaxf(m, __shfl_xor(m, dd));
        float p = __expf(lv - m);
        float s = p;
        #pragma unroll
        for (int dd = 1; dd < 64; dd <<= 1) s += __shfl_xor(s, dd);
        sm.att2[jj] = p / s;
    }
    lds_barrier();

    // P5a: xbar2 partials
    if (tid < FF*8) {
        int f = tid >> 3, c = tid & 7;
        float p = 0.f;
        #pragma unroll
        for (int u = 0; u < 8; u++) {
            int i = c*8 + u;
            p += sm.att2[i] * sm.xbarT[f*68 + i];
        }
        sm.part_x[f*8 + c] = p;
    }
    lds_barrier();

    // P5b: reduce xbar2
    if (tid < FF) {
        float s = 0.f;
        #pragma unroll
        for (int c = 0; c < 8; c++) s += sm.part_x[tid*8 + c];
        sm.xbar2[tid] = s;
    }
    lds_barrier();

    // P6': Xg0[r][j] = xbar2 . WXG0T[j] + bsum0[j]
    {
        float xb[FF];
        #pragma unroll
        for (int f = 0; f < FF; f++) xb[f] = sm.xbar2[f];
        #pragma unroll
        for (int half = 0; half < 2; half++) {
            int j = tid + half*256;
            const float4* wp = (const float4*)(ws + WS_WXG0T + j*20);
            float4 w0 = wp[0], w1 = wp[1], w2 = wp[2], w3 = wp[3];
            float wlast = ws[WS_WXG0T + j*20 + 16];
            float acc = ws[WS_BSUM + j];
            acc += w0.x*xb[0] + w0.y*xb[1] + w0.z*xb[2] + w0.w*xb[3];
            acc += w1.x*xb[4] + w1.y*xb[5] + w1.z*xb[6] + w1.w*xb[7];
            acc += w2.x*xb[8] + w2.y*xb[9] + w2.z*xb[10] + w2.w*xb[11];
            acc += w3.x*xb[12] + w3.y*xb[13] + w3.z*xb[14] + w3.w*xb[15];
            acc += wlast*xb[16];
            Xg[(size_t)r*GATES + j] = acc;
        }
    }
}

// ---------------- K2: all-layer pipelined recurrence, 1024 threads/block ----------------
// Grid: (BB, NLAYERS) = 256 blocks of 1024 threads (16 waves), 72 KB LDS,
// VGPR <= 128 (forced by 16-wave residency) -> 1 block/CU, all co-resident.
//
// WHY 1024 threads: the allocator's ~116-128 VGPR cap for 512-thr blocks is
// immovable (r2/r4/r5/r6), so 128 Whh floats/thread could never be resident
// (256 KB/block/step L2 restream = the measured ~320us aggregate wall). At
// 1024 threads each thread holds only 4 gates x 16 k = 64 Whh floats, and
// 64 + ~55 working regs FITS UNDER the 128 cap -> true residency, zero
// restream. TLP also doubles (4 waves/SIMD).
//
// Thread map: kc = tid>>7 (16-k slice), jj = tid&127 (gate sub-index).
//  - A: partials for gates {jj,128+jj,256+jj,384+jj} over k in [kc*16,+16):
//    16 readlane h-broadcasts + 64 FMA; write part[t&1][kc][jj] (float4).
//  - h ownership: lane L holds h[kc*16+(L&15)] (4-way redundant per wave,
//    2x across wave pairs); readlane(h_own, m) m<16 serves the A broadcast.
//  - B2 (all lanes, redundant): 8x float4 part reads (same-addr broadcast),
//    gate math, h_own/c_own update; store by lanes<16 of even waves.
//  - B1 (l>0): ingemm gate jg=(kc&3)*128+jj, timesteps (kc>>2)*4..+4 (4 acc
//    regs); Wih slice (4 float4 = one cache line) loaded JIT per step.
// One barrier per step; part[] double-buffered; r2's relaxed-flag + vmcnt(0)
// publish protocol.
__global__ __launch_bounds__(1024) void lstm_pipe(const float* __restrict__ Xg0,
                                                  const float* __restrict__ Wih,
                                                  const float* __restrict__ Whh,
                                                  float* __restrict__ ws) {
    const int b = blockIdx.x;
    const int l = blockIdx.y;
    const int tid = threadIdx.x;
    const int lane = tid & 63;
    const int w_ = tid >> 6;                 // wave 0..15
    const int kc = tid >> 7;                 // 0..7: 16-k slice
    const int jj = tid & 127;                // gate sub-index
    const int o = kc*16 + (lane & 15);       // owned h index (all lanes, redundant)
    const bool storer = ((w_ & 1) == 0) && (lane < 16);
    const int jg = (kc & 3)*128 + jj;        // ingemm gate
    const int tbase = (kc >> 2)*4;           // ingemm timestep base

    __shared__ __align__(16) float part[2][8][128][4];   // 32 KB
    __shared__ __align__(16) float xg[2][CH*GATES];      // 32 KB
    __shared__ __align__(16) float xs[2][CH*HID];        // 8 KB

    int* flags = (int*)(ws + WS_FLAGS);

    // Whh fragment -> registers: 4 gates x 16 k = 16 float4 = 64 VGPRs
    float4 w4[4][4];
    {
        const float* Whh_l = Whh + (size_t)l*GATES*HID;
        #pragma unroll
        for (int g = 0; g < 4; g++) {
            const float4* p = (const float4*)(Whh_l + (size_t)(g*128 + jj)*HID + kc*16);
            #pragma unroll
            for (int q = 0; q < 4; q++) w4[g][q] = p[q];
        }
    }

    const float* xg_g  = Xg0 + (size_t)b*TT*GATES;
    float*       hout  = ws + WS_HSEQ0 + (size_t)l*HSEQ_SZ + (size_t)b*TT*HID;
    const float* hprev = (l > 0) ? (ws + WS_HSEQ0 + (size_t)(l-1)*HSEQ_SZ + (size_t)b*TT*HID)
                                 : ws;
    const float4* wrg = (const float4*)(Wih + (size_t)l*GATES*HID + (size_t)jg*HID);
    const float  bsg = ws[WS_BSUM + l*GATES + jg];

    float h_own = 0.f, c_own = 0.f;
    float4 pf = {0,0,0,0};
    int buf = 0;
    float acc[4];

    if (l == 0) {
        // stage chunk 0 of Xg (4096 floats = 1 float4/thread)
        ((float4*)xg[0])[tid] = ((const float4*)xg_g)[tid];
        lds_barrier();
    } else {
        // prologue: wait chunk 0, stage xs[0] (1 float/thread), serial ingemm -> xg[0]
        if (tid == 0) {
            int* flg = &flags[(l-1)*BB + b];
            while (__hip_atomic_load(flg, __ATOMIC_RELAXED, __HIP_MEMORY_SCOPE_AGENT) < CH)
                __builtin_amdgcn_s_sleep(8);
        }
        lds_barrier();
        xs[0][tid] = __hip_atomic_load(&hprev[tid], __ATOMIC_RELAXED, __HIP_MEMORY_SCOPE_AGENT);
        lds_barrier();
        float a[4];
        #pragma unroll
        for (int u = 0; u < 4; u++) a[u] = bsg;
        for (int s = 0; s < CH; s++) {
            float4 q0 = wrg[s*4+0], q1 = wrg[s*4+1], q2 = wrg[s*4+2], q3 = wrg[s*4+3];
            #pragma unroll
            for (int u = 0; u < 4; u++) {
                const float4* xp = (const float4*)(&xs[0][(tbase+u)*HID + s*16]);
                float4 x0 = xp[0], x1 = xp[1], x2 = xp[2], x3 = xp[3];
                a[u] += q0.x*x0.x + q0.y*x0.y + q0.z*x0.z + q0.w*x0.w
                      + q1.x*x1.x + q1.y*x1.y + q1.z*x1.z + q1.w*x1.w
                      + q2.x*x2.x + q2.y*x2.y + q2.z*x2.z + q2.w*x2.w
                      + q3.x*x3.x + q3.y*x3.y + q3.z*x3.z + q3.w*x3.w;
            }
        }
        #pragma unroll
        for (int u = 0; u < 4; u++) {
            xg[0][(tbase+u)*GATES + jg] = a[u];
            acc[u] = bsg;
        }
        lds_barrier();
    }

    for (int c = 0; c < NCHUNK; c++) {
        const bool have_next = (c + 1 < NCHUNK);

        if (l == 0) {
            if (have_next) pf = ((const float4*)(xg_g + (size_t)(c+1)*CH*GATES))[tid];
        } else if (have_next) {
            // wait producer chunk c+1; stage into xs[(c+1)&1] (1 float/thread)
            if (tid == 0) {
                int* flg = &flags[(l-1)*BB + b];
                const int need = (c + 2)*CH;
                while (__hip_atomic_load(flg, __ATOMIC_RELAXED, __HIP_MEMORY_SCOPE_AGENT) < need)
                    __builtin_amdgcn_s_sleep(8);
            }
            lds_barrier();
            xs[(c+1)&1][tid] = __hip_atomic_load(&hprev[(size_t)(c+1)*CH*HID + tid],
                                                 __ATOMIC_RELAXED, __HIP_MEMORY_SCOPE_AGENT);
            // ds_write drained by step-0's A-barrier (lgkmcnt(0) before s_barrier)
        }

        const float* xgbuf = (l == 0) ? xg[buf] : xg[c & 1];
        const int nb_ = (c + 1) & 1;

        for (int tc = 0; tc < CH; tc++) {
            const int t = c*CH + tc;
            float xgc0 = xgbuf[tc*GATES + 0*HID + o];
            float xgc1 = xgbuf[tc*GATES + 1*HID + o];
            float xgc2 = xgbuf[tc*GATES + 2*HID + o];
            float xgc3 = xgbuf[tc*GATES + 3*HID + o];

            // A: Whh partial matvec; 16 readlane h-broadcasts + 64 FMA
            float a0 = 0.f, a1 = 0.f, a2 = 0.f, a3 = 0.f;
            #pragma unroll
            for (int q = 0; q < 4; q++) {
                float h0 = bcast_lane(h_own, q*4+0);
                float h1 = bcast_lane(h_own, q*4+1);
                float h2 = bcast_lane(h_own, q*4+2);
                float h3 = bcast_lane(h_own, q*4+3);
                a0 += w4[0][q].x*h0 + w4[0][q].y*h1 + w4[0][q].z*h2 + w4[0][q].w*h3;
                a1 += w4[1][q].x*h0 + w4[1][q].y*h1 + w4[1][q].z*h2 + w4[1][q].w*h3;
                a2 += w4[2][q].x*h0 + w4[2][q].y*h1 + w4[2][q].z*h2 + w4[2][q].w*h3;
                a3 += w4[3][q].x*h0 + w4[3][q].y*h1 + w4[3][q].z*h2 + w4[3][q].w*h3;
            }
            float4 st = {a0, a1, a2, a3};
            *(float4*)(&part[t & 1][kc][jj][0]) = st;

            lds_barrier();

            // B2: all lanes (redundant) update h[o]; storers write to global
            {
                float4 p0 = *(const float4*)(&part[t & 1][0][o][0]);
                float4 p1 = *(const float4*)(&part[t & 1][1][o][0]);
                float4 p2 = *(const float4*)(&part[t & 1][2][o][0]);
                float4 p3 = *(const float4*)(&part[t & 1][3][o][0]);
                float4 p4 = *(const float4*)(&part[t & 1][4][o][0]);
                float4 p5 = *(const float4*)(&part[t & 1][5][o][0]);
                float4 p6 = *(const float4*)(&part[t & 1][6][o][0]);
                float4 p7 = *(const float4*)(&part[t & 1][7][o][0]);
                float gi = xgc0 + (((p0.x+p1.x)+(p2.x+p3.x)) + ((p4.x+p5.x)+(p6.x+p7.x)));
                float gf = xgc1 + (((p0.y+p1.y)+(p2.y+p3.y)) + ((p4.y+p5.y)+(p6.y+p7.y)));
                float gg = xgc2 + (((p0.z+p1.z)+(p2.z+p3.z)) + ((p4.z+p5.z)+(p6.z+p7.z)));
                float go = xgc3 + (((p0.w+p1.w)+(p2.w+p3.w)) + ((p4.w+p5.w)+(p6.w+p7.w)));
                float si = fsig(gi), sf = fsig(gf), so = fsig(go);
                float tg = ftanh(gg);
                c_own = sf*c_own + si*tg;
                h_own = so*ftanh(c_own);
                if (storer)
                    __hip_atomic_store(&hout[t*HID + o], h_own,
                                       __ATOMIC_RELAXED, __HIP_MEMORY_SCOPE_AGENT);
            }

            // B1: ingemm slice tc for chunk c+1 (Wih slice = one cache line, JIT)
            if (l > 0 && have_next) {
                float4 wv0 = wrg[tc*4+0], wv1 = wrg[tc*4+1], wv2 = wrg[tc*4+2], wv3 = wrg[tc*4+3];
                #pragma unroll
                for (int u = 0; u < 4; u++) {
                    const float4* xp = (const float4*)(&xs[nb_][(tbase+u)*HID + tc*16]);
                    float4 x0 = xp[0], x1 = xp[1], x2 = xp[2], x3 = xp[3];
                    acc[u] += wv0.x*x0.x + wv0.y*x0.y + wv0.z*x0.z + wv0.w*x0.w
                            + wv1.x*x1.x + wv1.y*x1.y + wv1.z*x1.z + wv1.w*x1.w
                            + wv2.x*x2.x + wv2.y*x2.y + wv2.z*x2.z + wv2.w*x2.w
                            + wv3.x*x3.x + wv3.y*x3.y + wv3.z*x3.z + wv3.w*x3.w;
                }
                if (tc == CH - 1) {
                    #pragma unroll
                    for (int u = 0; u < 4; u++) {
                        xg[nb_][(tbase+u)*GATES + jg] = acc[u];
                        acc[u] = bsg;
                    }
                }
            }
        }

        // chunk end: drain h stores, barrier (xg/xs rotation safety), publish
        if (l == 0) {
            __asm__ volatile("s_waitcnt vmcnt(0)" ::: "memory");   // h stores + pf load done
            if (have_next) {
                ((float4*)xg[buf ^ 1])[tid] = pf;
                buf ^= 1;
            }
            lds_barrier();
            if (tid == 0)
                __hip_atomic_store(&flags[b], (c+1)*CH,
                                   __ATOMIC_RELAXED, __HIP_MEMORY_SCOPE_AGENT);
        } else {
            __asm__ volatile("s_waitcnt vmcnt(0)" ::: "memory");   // h stores done
            lds_barrier();
            if (l < NLAYERS - 1 && tid == 0)
                __hip_atomic_store(&flags[l*BB + b], (c+1)*CH,
                                   __ATOMIC_RELAXED, __HIP_MEMORY_SCOPE_AGENT);
        }
    }
}

// ---------------- K4: final linear ----------------
__global__ void final_lin(const float* __restrict__ ws, const float* __restrict__ Wlin,
                          const float* __restrict__ blin, float* __restrict__ out) {
    const int b = blockIdx.x, l = threadIdx.x;  // 64 threads
    float acc = 0.f;
    #pragma unroll
    for (int u = 0; u < 8; u++) {
        int idx = u*64 + l;
        int layer = idx >> 7, k = idx & 127;
        const float* hs = ws + WS_HSEQ0 + (size_t)layer*HSEQ_SZ;
        acc += hs[((size_t)b*TT + (TT-1))*HID + k] * Wlin[idx];
    }
    #pragma unroll
    for (int d = 1; d < 64; d <<= 1) acc += __shfl_xor(acc, d);
    if (l == 0) out[b] = acc + blin[0];
}

extern "C" void kernel_launch(void* const* d_in, const int* in_sizes, int n_in,
                              void* d_out, int out_size, void* d_ws, size_t ws_size,
                              hipStream_t stream) {
    const float* x    = (const float*)d_in[0];
    const int*   adj  = (const int*)d_in[1];
    const float* W1   = (const float*)d_in[2];
    const float* a1   = (const float*)d_in[3];
    const float* W2   = (const float*)d_in[4];
    const float* a2   = (const float*)d_in[5];
    const float* Wih  = (const float*)d_in[6];
    const float* Whh  = (const float*)d_in[7];
    const float* bih  = (const float*)d_in[8];
    const float* bhh  = (const float*)d_in[9];
    const float* Wlin = (const float*)d_in[10];
    const float* blin = (const float*)d_in[11];
    const int*   site = (const int*)d_in[12];
    float* ws  = (float*)d_ws;
    float* out = (float*)d_out;

    prep1<<<1, 256, 0, stream>>>(W1, a1, W2, a2, bih, bhh, adj, ws);
    prep2<<<FF, 128, 0, stream>>>(W1, W2, ws);
    prep3<<<35, 256, 0, stream>>>(W1, Wih, ws);
    gat_fused<<<dim3(TT, BB), 256, 0, stream>>>(x, adj, ws, ws + WS_XG, site);
    // all 4 layers concurrently, wavefront-pipelined via agent-scope flags;
    // 1024-thr blocks: Whh fully register-resident (64 VGPR/thread)
    lstm_pipe<<<dim3(BB, NLAYERS), 1024, 0, stream>>>(ws + WS_XG, Wih, Whh, ws);
    final_lin<<<64, 64, 0, stream>>>(ws, Wlin, blin, out);
}

// Round 11
// 1309.255 us; speedup vs baseline: 1.0015x; 1.0015x over previous
//
#include <hip/hip_runtime.h>
#include <hip/hip_bf16.h>

// Problem dims
#define BB 64
#define TT 168
#define NN 64
#define FF 17
#define HID 128
#define GATES 512   // 4*HID
#define NLAYERS 4
#define NROWS (BB*TT)   // 10752

// LSTM pipeline chunking
#define CH 8
#define NCHUNK (TT/CH)  // 21

// Workspace layout (float offsets)
#define WS_W1SRC 0
#define WS_W1DST 32
#define WS_W2SRC 64
#define WS_W2DST 192
#define WS_BSUM  320                    // 4*512 -> ends 2368
#define WS_WD    2560                   // 17 (pad 32): W1 @ (W2 @ a2dst)
#define WS_WSV   2592                   // 17 (pad 32): W1 @ (W2 @ a2src)
#define WS_W12   2624                   // 17*128 = 2176: W1 @ W2
#define WS_WXG0T 4800                   // 512*20 (17 used): (W12 @ Wih0^T)^T rows -> ends 15040
#define WS_ADJB  15104                  // 64 u64 adjacency bitmasks (128 floats) -> ends 15232
#define WS_FLAGS 16000                  // 256 ints: per-(layer,batch) progress counters
#define WS_XG    1395712                // NROWS*512 = 5505024 (layer-0 gates from GAT)
#define WS_HSEQ0 6900736                // 4 buffers of NROWS*HID
#define HSEQ_SZ  1376256

// LDS-only barrier: s_waitcnt lgkmcnt(0) + raw s_barrier (no vmcnt drain).
__device__ __forceinline__ void lds_barrier() {
    __asm__ volatile("" ::: "memory");
    __builtin_amdgcn_s_waitcnt(0xc07f);
    __builtin_amdgcn_s_barrier();
    __asm__ volatile("" ::: "memory");
}

__device__ __forceinline__ float fsig(float x) {
    return __builtin_amdgcn_rcpf(1.f + __expf(-x));
}
__device__ __forceinline__ float ftanh(float x) {
    float e = __expf(2.f * x);
    return 1.f - 2.f * __builtin_amdgcn_rcpf(e + 1.f);
}
__device__ __forceinline__ float bcast_lane(float v, int lane) {
    return __int_as_float(__builtin_amdgcn_readlane(__float_as_int(v), lane));
}

// ---------------- prep1: attention projection vectors + bias sums + adj bitmasks + flag reset ----------------
__global__ void prep1(const float* __restrict__ W1, const float* __restrict__ a1,
                      const float* __restrict__ W2, const float* __restrict__ a2,
                      const float* __restrict__ bih, const float* __restrict__ bhh,
                      const int* __restrict__ adj, float* __restrict__ ws) {
    int tid = threadIdx.x;
    if (tid < 34) {
        int f = tid % FF, half = tid / FF;
        float acc = 0.f;
        for (int o = 0; o < HID; o++) acc += W1[f*HID + o] * a1[half*HID + o];
        ws[(half ? WS_W1DST : WS_W1SRC) + f] = acc;
    }
    {
        int k = tid & 127, half = tid >> 7;
        float acc = 0.f;
        for (int o = 0; o < HID; o++) acc += W2[k*HID + o] * a2[half*HID + o];
        ws[(half ? WS_W2DST : WS_W2SRC) + k] = acc;
    }
    for (int idx = tid; idx < NLAYERS*GATES; idx += 256) ws[WS_BSUM + idx] = bih[idx] + bhh[idx];
    // adjacency bitmasks (with self-loop), computed once for all 10752 GAT blocks
    if (tid < 64) {
        unsigned long long m = 1ull << tid;
        const int* ar = adj + tid*64;
        for (int j = 0; j < 64; j++) if (ar[j] > 0) m |= (1ull << j);
        ((unsigned long long*)(ws + WS_ADJB))[tid] = m;
    }
    // reset pipeline flags (agent-scope so lstm_pipe's coherent loads see zeros)
    __hip_atomic_store((int*)(ws + WS_FLAGS) + tid, 0,
                       __ATOMIC_RELAXED, __HIP_MEMORY_SCOPE_AGENT);
}

// ---------------- prep2: W12 = W1 @ W2 (17 x 128) ----------------
__global__ void prep2(const float* __restrict__ W1, const float* __restrict__ W2,
                      float* __restrict__ ws) {
    int f = blockIdx.x, o = threadIdx.x;
    float acc = 0.f;
    for (int k = 0; k < HID; k++) acc += W1[f*HID + k] * W2[k*HID + o];
    ws[WS_W12 + f*HID + o] = acc;
}

// ---------------- prep3: WD/WSV (17 each) + WXG0T (512 x 17, stride 20) ----------------
__global__ void prep3(const float* __restrict__ W1, const float* __restrict__ Wih0,
                      float* __restrict__ ws) {
    int idx = blockIdx.x * 256 + threadIdx.x;
    if (idx < 17) {
        int f = idx;
        float acc = 0.f;
        for (int k = 0; k < HID; k++) acc += W1[f*HID + k] * ws[WS_W2DST + k];
        ws[WS_WD + f] = acc;
    } else if (idx < 34) {
        int f = idx - 17;
        float acc = 0.f;
        for (int k = 0; k < HID; k++) acc += W1[f*HID + k] * ws[WS_W2SRC + k];
        ws[WS_WSV + f] = acc;
    } else if (idx < 34 + GATES*FF) {
        int e = idx - 34;
        int j = e % GATES, f = e / GATES;   // f < 17
        float acc = 0.f;
        for (int o = 0; o < HID; o++) acc += ws[WS_W12 + f*HID + o] * Wih0[j*HID + o];
        ws[WS_WXG0T + j*20 + f] = acc;
    }
}

// ---------------- K1: fused GAT1 + GAT2(site) -> Xg layer-0 directly ----------------
struct __align__(16) GatSmem {
    float attn[64*68];       // P2 writes rows (stride 68), P3 reads
    float xsT[FF*64];        // [f][n]
    float xbarT[FF*68];      // [f][i], stride 68
    float src1[64], dst1[64], rinv[64], att2[64];
    float xbar2[20];
    float part_x[FF*8];      // P5a partials
    unsigned long long adjbits[64];
};
// ~28.5 KB -> 5 blocks/CU

__global__ __launch_bounds__(256) void gat_fused(const float* __restrict__ x, const int* __restrict__ adj,
                                                 const float* __restrict__ ws,
                                                 float* __restrict__ Xg, const int* __restrict__ site_ptr) {
    __shared__ GatSmem sm;
    const int tid = threadIdx.x;
    const int tt = blockIdx.x, bb = blockIdx.y;
    const int site = site_ptr[0];
    const int r = bb*TT + tt;
    const float* xblk = x + (size_t)r * (NN*FF);

    // P0: x transposed into LDS, adjacency bitmasks from prep1
    for (int idx = tid; idx < NN*FF; idx += 256) {
        int n = idx / FF, f = idx % FF;
        sm.xsT[f*64 + n] = xblk[idx];
    }
    if (tid < 64) sm.adjbits[tid] = ((const unsigned long long*)(ws + WS_ADJB))[tid];
    lds_barrier();

    // P1: src1/dst1 = x . (W1 @ a1-halves)
    if (tid < 128) {
        int n = tid & 63, half = tid >> 6;
        const float* wv = ws + (half ? WS_W1DST : WS_W1SRC);
        float acc = 0.f;
        #pragma unroll
        for (int f = 0; f < FF; f++) acc += sm.xsT[f*64 + n] * wv[f];
        if (half) sm.dst1[n] = acc; else sm.src1[n] = acc;
    }
    lds_barrier();

    // P2: attention logits -> exp -> attn rows
    {
        int q = tid & 3, i = tid >> 2;
        unsigned long long ab = sm.adjbits[i];
        float si = sm.src1[i];
        float v[16];
        float vmax = -1e30f;
        #pragma unroll
        for (int u = 0; u < 16; u++) {
            int jj = q*16 + u;
            float e = si + sm.dst1[jj];
            float lv = fmaxf(e, 0.2f*e);
            lv = ((ab >> jj) & 1ull) ? lv : -1e9f;
            v[u] = lv;
            vmax = fmaxf(vmax, lv);
        }
        vmax = fmaxf(vmax, __shfl_xor(vmax, 1, 4));
        vmax = fmaxf(vmax, __shfl_xor(vmax, 2, 4));
        float s = 0.f;
        float* arow = &sm.attn[i*68];
        #pragma unroll
        for (int w = 0; w < 4; w++) {
            float4 pv;
            pv.x = __expf(v[w*4+0] - vmax);
            pv.y = __expf(v[w*4+1] - vmax);
            pv.z = __expf(v[w*4+2] - vmax);
            pv.w = __expf(v[w*4+3] - vmax);
            s += (pv.x + pv.y) + (pv.z + pv.w);
            *(float4*)(arow + q*16 + w*4) = pv;
        }
        s += __shfl_xor(s, 1, 4);
        s += __shfl_xor(s, 2, 4);
        if (q == 0) sm.rinv[i] = 1.f / s;
    }
    lds_barrier();

    // P3: xbarT[f][i] = (P @ X)[i][f] * rinv
    {
        int i = tid & 63, q = tid >> 6;
        const float* arow = &sm.attn[i*68];
        float acc[5] = {0.f,0.f,0.f,0.f,0.f};
        const int nf = (q == 0) ? 5 : 4;
        for (int j4 = 0; j4 < 16; j4++) {
            float4 a4 = *(const float4*)(arow + j4*4);
            #pragma unroll
            for (int u = 0; u < 5; u++) {
                if (u < nf) {
                    int f = q + 4*u;
                    float4 x4 = *(const float4*)(&sm.xsT[f*64 + j4*4]);
                    acc[u] += a4.x*x4.x + a4.y*x4.y + a4.z*x4.z + a4.w*x4.w;
                }
            }
        }
        float ri = sm.rinv[i];
        #pragma unroll
        for (int u = 0; u < 5; u++) {
            if (u < nf) sm.xbarT[(q + 4*u)*68 + i] = acc[u] * ri;
        }
    }
    lds_barrier();

    // P4' (wave 0): dst2[j] = xbar[j].WD ; src2 = xbar[site].WSV ; softmax -> att2
    if (tid < 64) {
        int jj = tid;
        float d = 0.f, sp = 0.f;
        #pragma unroll
        for (int f = 0; f < FF; f++) {
            float xv = sm.xbarT[f*68 + jj];
            float xsv = sm.xbarT[f*68 + site];
            d  += xv * ws[WS_WD + f];
            sp += xsv * ws[WS_WSV + f];
        }
        unsigned long long ab = sm.adjbits[site];
        float e = sp + d;
        float lv = fmaxf(e, 0.2f*e);
        lv = ((ab >> jj) & 1ull) ? lv : -1e9f;
        float m = lv;
        #pragma unroll
        for (int dd = 1; dd < 64; dd <<= 1) m = fmaxf(m, __shfl_xor(m, dd));
        float p = __expf(lv - m);
        float s = p;
        #pragma unroll
        for (int dd = 1; dd < 64; dd <<= 1) s += __shfl_xor(s, dd);
        sm.att2[jj] = p / s;
    }
    lds_barrier();

    // P5a: xbar2 partials
    if (tid < FF*8) {
        int f = tid >> 3, c = tid & 7;
        float p = 0.f;
        #pragma unroll
        for (int u = 0; u < 8; u++) {
            int i = c*8 + u;
            p += sm.att2[i] * sm.xbarT[f*68 + i];
        }
        sm.part_x[f*8 + c] = p;
    }
    lds_barrier();

    // P5b: reduce xbar2
    if (tid < FF) {
        float s = 0.f;
        #pragma unroll
        for (int c = 0; c < 8; c++) s += sm.part_x[tid*8 + c];
        sm.xbar2[tid] = s;
    }
    lds_barrier();

    // P6': Xg0[r][j] = xbar2 . WXG0T[j] + bsum0[j]
    {
        float xb[FF];
        #pragma unroll
        for (int f = 0; f < FF; f++) xb[f] = sm.xbar2[f];
        #pragma unroll
        for (int half = 0; half < 2; half++) {
            int j = tid + half*256;
            const float4* wp = (const float4*)(ws + WS_WXG0T + j*20);
            float4 w0 = wp[0], w1 = wp[1], w2 = wp[2], w3 = wp[3];
            float wlast = ws[WS_WXG0T + j*20 + 16];
            float acc = ws[WS_BSUM + j];
            acc += w0.x*xb[0] + w0.y*xb[1] + w0.z*xb[2] + w0.w*xb[3];
            acc += w1.x*xb[4] + w1.y*xb[5] + w1.z*xb[6] + w1.w*xb[7];
            acc += w2.x*xb[8] + w2.y*xb[9] + w2.z*xb[10] + w2.w*xb[11];
            acc += w3.x*xb[12] + w3.y*xb[13] + w3.z*xb[14] + w3.w*xb[15];
            acc += wlast*xb[16];
            Xg[(size_t)r*GATES + j] = acc;
        }
    }
}

// ---------------- K2: all-layer pipelined recurrence, 1024 threads/block ----------------
// Grid: (BB, NLAYERS) = 256 blocks of 1024 threads (16 waves), 84 KB LDS,
// 1 block/CU (forced by LDS: 2x84KB > 160KB), 4 waves/SIMD, VGPR budget
// 512/4 = 128.
//
// Round-9 failure mode: 72 KB LDS allowed 2 blocks/CU -> allocator targeted
// 8 waves/SIMD -> VGPR capped at 64 -> the 64-float Whh + ~50 working regs
// (demand ~110) spilled wholesale (FETCH 369 MB, WRITE 238 MB of scratch).
// Fix: pad LDS to 84 KB so 2-block occupancy is infeasible -> the allocator's
// occupancy-derived budget is 128 (= 512/4), and demand ~110-120 fits ->
// Whh genuinely loop-resident, zero restream. waves_per_eu(4,4) reinforces.
//
// Thread map: kc = tid>>7 (16-k slice), jj = tid&127 (gate sub-index).
//  - A: partials for gates {jj,128+jj,256+jj,384+jj} over k in [kc*16,+16):
//    16 readlane h-broadcasts + 64 FMA; write part[t&1][kc][jj] (float4).
//  - h ownership: lane L holds h[kc*16+(L&15)] (redundant within wave);
//    readlane(h_own, m) m<16 serves the A broadcast.
//  - B2 (all lanes, redundant): 8x float4 part reads (broadcast), gate math,
//    h_own/c_own update; store by lanes<16 of even waves.
//  - B1 (l>0): ingemm gate jg=(kc&3)*128+jj, timesteps (kc>>2)*4..+4 (4 acc
//    regs); Wih slice (4 float4 = one cache line) loaded JIT per step.
// One barrier per step; part[] double-buffered; r2's relaxed-flag + vmcnt(0)
// publish protocol. Logic byte-identical to round-9's passed (absmax=0) run.
__global__ __launch_bounds__(1024)
__attribute__((amdgpu_waves_per_eu(4, 4)))
void lstm_pipe(const float* __restrict__ Xg0,
               const float* __restrict__ Wih,
               const float* __restrict__ Whh,
               float* __restrict__ ws) {
    const int b = blockIdx.x;
    const int l = blockIdx.y;
    const int tid = threadIdx.x;
    const int lane = tid & 63;
    const int w_ = tid >> 6;                 // wave 0..15
    const int kc = tid >> 7;                 // 0..7: 16-k slice
    const int jj = tid & 127;                // gate sub-index
    const int o = kc*16 + (lane & 15);       // owned h index (all lanes, redundant)
    const bool storer = ((w_ & 1) == 0) && (lane < 16);
    const int jg = (kc & 3)*128 + jj;        // ingemm gate
    const int tbase = (kc >> 2)*4;           // ingemm timestep base

    __shared__ __align__(16) float part[2][8][128][4];   // 32 KB
    __shared__ __align__(16) float xg[2][CH*GATES];      // 32 KB
    __shared__ __align__(16) float xs[2][CH*HID];        // 8 KB
    __shared__ __align__(16) float lds_pad[3072];        // 12 KB: occupancy forcing (runtime-dead)

    int* flags = (int*)(ws + WS_FLAGS);

    // Runtime-never-true guard keeps lds_pad allocated (flags[255] is only ever 0).
    if (__hip_atomic_load(&flags[255], __ATOMIC_RELAXED, __HIP_MEMORY_SCOPE_AGENT) == 0x7fffffff) {
        lds_pad[tid & 2047] = (float)tid;
        __builtin_amdgcn_s_waitcnt(0xc07f);
        ((float*)ws)[tid] = lds_pad[(tid ^ 1) & 2047];
    }

    // Whh fragment -> registers: 4 gates x 16 k = 16 float4 = 64 VGPRs
    float4 w4[4][4];
    {
        const float* Whh_l = Whh + (size_t)l*GATES*HID;
        #pragma unroll
        for (int g = 0; g < 4; g++) {
            const float4* p = (const float4*)(Whh_l + (size_t)(g*128 + jj)*HID + kc*16);
            #pragma unroll
            for (int q = 0; q < 4; q++) w4[g][q] = p[q];
        }
    }

    const float* xg_g  = Xg0 + (size_t)b*TT*GATES;
    float*       hout  = ws + WS_HSEQ0 + (size_t)l*HSEQ_SZ + (size_t)b*TT*HID;
    const float* hprev = (l > 0) ? (ws + WS_HSEQ0 + (size_t)(l-1)*HSEQ_SZ + (size_t)b*TT*HID)
                                 : ws;
    const float4* wrg = (const float4*)(Wih + (size_t)l*GATES*HID + (size_t)jg*HID);
    const float  bsg = ws[WS_BSUM + l*GATES + jg];

    float h_own = 0.f, c_own = 0.f;
    float4 pf = {0,0,0,0};
    int buf = 0;
    float acc[4];

    if (l == 0) {
        // stage chunk 0 of Xg (4096 floats = 1 float4/thread)
        ((float4*)xg[0])[tid] = ((const float4*)xg_g)[tid];
        lds_barrier();
    } else {
        // prologue: wait chunk 0, stage xs[0] (1 float/thread), serial ingemm -> xg[0]
        if (tid == 0) {
            int* flg = &flags[(l-1)*BB + b];
            while (__hip_atomic_load(flg, __ATOMIC_RELAXED, __HIP_MEMORY_SCOPE_AGENT) < CH)
                __builtin_amdgcn_s_sleep(8);
        }
        lds_barrier();
        xs[0][tid] = __hip_atomic_load(&hprev[tid], __ATOMIC_RELAXED, __HIP_MEMORY_SCOPE_AGENT);
        lds_barrier();
        float a[4];
        #pragma unroll
        for (int u = 0; u < 4; u++) a[u] = bsg;
        for (int s = 0; s < CH; s++) {
            float4 q0 = wrg[s*4+0], q1 = wrg[s*4+1], q2 = wrg[s*4+2], q3 = wrg[s*4+3];
            #pragma unroll
            for (int u = 0; u < 4; u++) {
                const float4* xp = (const float4*)(&xs[0][(tbase+u)*HID + s*16]);
                float4 x0 = xp[0], x1 = xp[1], x2 = xp[2], x3 = xp[3];
                a[u] += q0.x*x0.x + q0.y*x0.y + q0.z*x0.z + q0.w*x0.w
                      + q1.x*x1.x + q1.y*x1.y + q1.z*x1.z + q1.w*x1.w
                      + q2.x*x2.x + q2.y*x2.y + q2.z*x2.z + q2.w*x2.w
                      + q3.x*x3.x + q3.y*x3.y + q3.z*x3.z + q3.w*x3.w;
            }
        }
        #pragma unroll
        for (int u = 0; u < 4; u++) {
            xg[0][(tbase+u)*GATES + jg] = a[u];
            acc[u] = bsg;
        }
        lds_barrier();
    }

    for (int c = 0; c < NCHUNK; c++) {
        const bool have_next = (c + 1 < NCHUNK);

        if (l == 0) {
            if (have_next) pf = ((const float4*)(xg_g + (size_t)(c+1)*CH*GATES))[tid];
        } else if (have_next) {
            // wait producer chunk c+1; stage into xs[(c+1)&1] (1 float/thread)
            if (tid == 0) {
                int* flg = &flags[(l-1)*BB + b];
                const int need = (c + 2)*CH;
                while (__hip_atomic_load(flg, __ATOMIC_RELAXED, __HIP_MEMORY_SCOPE_AGENT) < need)
                    __builtin_amdgcn_s_sleep(8);
            }
            lds_barrier();
            xs[(c+1)&1][tid] = __hip_atomic_load(&hprev[(size_t)(c+1)*CH*HID + tid],
                                                 __ATOMIC_RELAXED, __HIP_MEMORY_SCOPE_AGENT);
            // ds_write drained by step-0's A-barrier (lgkmcnt(0) before s_barrier)
        }

        const float* xgbuf = (l == 0) ? xg[buf] : xg[c & 1];
        const int nb_ = (c + 1) & 1;

        for (int tc = 0; tc < CH; tc++) {
            const int t = c*CH + tc;
            float xgc0 = xgbuf[tc*GATES + 0*HID + o];
            float xgc1 = xgbuf[tc*GATES + 1*HID + o];
            float xgc2 = xgbuf[tc*GATES + 2*HID + o];
            float xgc3 = xgbuf[tc*GATES + 3*HID + o];

            // A: Whh partial matvec; 16 readlane h-broadcasts + 64 FMA
            float a0 = 0.f, a1 = 0.f, a2 = 0.f, a3 = 0.f;
            #pragma unroll
            for (int q = 0; q < 4; q++) {
                float h0 = bcast_lane(h_own, q*4+0);
                float h1 = bcast_lane(h_own, q*4+1);
                float h2 = bcast_lane(h_own, q*4+2);
                float h3 = bcast_lane(h_own, q*4+3);
                a0 += w4[0][q].x*h0 + w4[0][q].y*h1 + w4[0][q].z*h2 + w4[0][q].w*h3;
                a1 += w4[1][q].x*h0 + w4[1][q].y*h1 + w4[1][q].z*h2 + w4[1][q].w*h3;
                a2 += w4[2][q].x*h0 + w4[2][q].y*h1 + w4[2][q].z*h2 + w4[2][q].w*h3;
                a3 += w4[3][q].x*h0 + w4[3][q].y*h1 + w4[3][q].z*h2 + w4[3][q].w*h3;
            }
            float4 st = {a0, a1, a2, a3};
            *(float4*)(&part[t & 1][kc][jj][0]) = st;

            lds_barrier();

            // B2: all lanes (redundant) update h[o]; storers write to global
            {
                float4 p0 = *(const float4*)(&part[t & 1][0][o][0]);
                float4 p1 = *(const float4*)(&part[t & 1][1][o][0]);
                float4 p2 = *(const float4*)(&part[t & 1][2][o][0]);
                float4 p3 = *(const float4*)(&part[t & 1][3][o][0]);
                float4 p4 = *(const float4*)(&part[t & 1][4][o][0]);
                float4 p5 = *(const float4*)(&part[t & 1][5][o][0]);
                float4 p6 = *(const float4*)(&part[t & 1][6][o][0]);
                float4 p7 = *(const float4*)(&part[t & 1][7][o][0]);
                float gi = xgc0 + (((p0.x+p1.x)+(p2.x+p3.x)) + ((p4.x+p5.x)+(p6.x+p7.x)));
                float gf = xgc1 + (((p0.y+p1.y)+(p2.y+p3.y)) + ((p4.y+p5.y)+(p6.y+p7.y)));
                float gg = xgc2 + (((p0.z+p1.z)+(p2.z+p3.z)) + ((p4.z+p5.z)+(p6.z+p7.z)));
                float go = xgc3 + (((p0.w+p1.w)+(p2.w+p3.w)) + ((p4.w+p5.w)+(p6.w+p7.w)));
                float si = fsig(gi), sf = fsig(gf), so = fsig(go);
                float tg = ftanh(gg);
                c_own = sf*c_own + si*tg;
                h_own = so*ftanh(c_own);
                if (storer)
                    __hip_atomic_store(&hout[t*HID + o], h_own,
                                       __ATOMIC_RELAXED, __HIP_MEMORY_SCOPE_AGENT);
            }

            // B1: ingemm slice tc for chunk c+1 (Wih slice = one cache line, JIT)
            if (l > 0 && have_next) {
                float4 wv0 = wrg[tc*4+0], wv1 = wrg[tc*4+1], wv2 = wrg[tc*4+2], wv3 = wrg[tc*4+3];
                #pragma unroll
                for (int u = 0; u < 4; u++) {
                    const float4* xp = (const float4*)(&xs[nb_][(tbase+u)*HID + tc*16]);
                    float4 x0 = xp[0], x1 = xp[1], x2 = xp[2], x3 = xp[3];
                    acc[u] += wv0.x*x0.x + wv0.y*x0.y + wv0.z*x0.z + wv0.w*x0.w
                            + wv1.x*x1.x + wv1.y*x1.y + wv1.z*x1.z + wv1.w*x1.w
                            + wv2.x*x2.x + wv2.y*x2.y + wv2.z*x2.z + wv2.w*x2.w
                            + wv3.x*x3.x + wv3.y*x3.y + wv3.z*x3.z + wv3.w*x3.w;
                }
                if (tc == CH - 1) {
                    #pragma unroll
                    for (int u = 0; u < 4; u++) {
                        xg[nb_][(tbase+u)*GATES + jg] = acc[u];
                        acc[u] = bsg;
                    }
                }
            }
        }

        // chunk end: drain h stores, barrier (xg/xs rotation safety), publish
        if (l == 0) {
            __asm__ volatile("s_waitcnt vmcnt(0)" ::: "memory");   // h stores + pf load done
            if (have_next) {
                ((float4*)xg[buf ^ 1])[tid] = pf;
                buf ^= 1;
            }
            lds_barrier();
            if (tid == 0)
                __hip_atomic_store(&flags[b], (c+1)*CH,
                                   __ATOMIC_RELAXED, __HIP_MEMORY_SCOPE_AGENT);
        } else {
            __asm__ volatile("s_waitcnt vmcnt(0)" ::: "memory");   // h stores done
            lds_barrier();
            if (l < NLAYERS - 1 && tid == 0)
                __hip_atomic_store(&flags[l*BB + b], (c+1)*CH,
                                   __ATOMIC_RELAXED, __HIP_MEMORY_SCOPE_AGENT);
        }
    }
}

// ---------------- K4: final linear ----------------
__global__ void final_lin(const float* __restrict__ ws, const float* __restrict__ Wlin,
                          const float* __restrict__ blin, float* __restrict__ out) {
    const int b = blockIdx.x, l = threadIdx.x;  // 64 threads
    float acc = 0.f;
    #pragma unroll
    for (int u = 0; u < 8; u++) {
        int idx = u*64 + l;
        int layer = idx >> 7, k = idx & 127;
        const float* hs = ws + WS_HSEQ0 + (size_t)layer*HSEQ_SZ;
        acc += hs[((size_t)b*TT + (TT-1))*HID + k] * Wlin[idx];
    }
    #pragma unroll
    for (int d = 1; d < 64; d <<= 1) acc += __shfl_xor(acc, d);
    if (l == 0) out[b] = acc + blin[0];
}

extern "C" void kernel_launch(void* const* d_in, const int* in_sizes, int n_in,
                              void* d_out, int out_size, void* d_ws, size_t ws_size,
                              hipStream_t stream) {
    const float* x    = (const float*)d_in[0];
    const int*   adj  = (const int*)d_in[1];
    const float* W1   = (const float*)d_in[2];
    const float* a1   = (const float*)d_in[3];
    const float* W2   = (const float*)d_in[4];
    const float* a2   = (const float*)d_in[5];
    const float* Wih  = (const float*)d_in[6];
    const float* Whh  = (const float*)d_in[7];
    const float* bih  = (const float*)d_in[8];
    const float* bhh  = (const float*)d_in[9];
    const float* Wlin = (const float*)d_in[10];
    const float* blin = (const float*)d_in[11];
    const int*   site = (const int*)d_in[12];
    float* ws  = (float*)d_ws;
    float* out = (float*)d_out;

    prep1<<<1, 256, 0, stream>>>(W1, a1, W2, a2, bih, bhh, adj, ws);
    prep2<<<FF, 128, 0, stream>>>(W1, W2, ws);
    prep3<<<35, 256, 0, stream>>>(W1, Wih, ws);
    gat_fused<<<dim3(TT, BB), 256, 0, stream>>>(x, adj, ws, ws + WS_XG, site);
    // all 4 layers concurrently, wavefront-pipelined via agent-scope flags;
    // 1024-thr blocks: Whh register-resident (64 VGPR/thread), 128-reg budget
    lstm_pipe<<<dim3(BB, NLAYERS), 1024, 0, stream>>>(ws + WS_XG, Wih, Whh, ws);
    final_lin<<<64, 64, 0, stream>>>(ws, Wlin, blin, out);
}

// Round 12
// 777.970 us; speedup vs baseline: 1.6854x; 1.6829x over previous
//
#include <hip/hip_runtime.h>
#include <hip/hip_bf16.h>

// Problem dims
#define BB 64
#define TT 168
#define NN 64
#define FF 17
#define HID 128
#define GATES 512   // 4*HID
#define NLAYERS 4
#define NROWS (BB*TT)   // 10752

// LSTM pipeline chunking
#define CH 8
#define NCHUNK (TT/CH)  // 21

// Workspace layout (float offsets)
#define WS_W1SRC 0
#define WS_W1DST 32
#define WS_W2SRC 64
#define WS_W2DST 192
#define WS_BSUM  320                    // 4*512 -> ends 2368
#define WS_WD    2560                   // 17 (pad 32): W1 @ (W2 @ a2dst)
#define WS_WSV   2592                   // 17 (pad 32): W1 @ (W2 @ a2src)
#define WS_W12   2624                   // 17*128 = 2176: W1 @ W2
#define WS_WXG0T 4800                   // 512*20 (17 used): (W12 @ Wih0^T)^T rows -> ends 15040
#define WS_ADJB  15104                  // 64 u64 adjacency bitmasks (128 floats) -> ends 15232
#define WS_FLAGS 16000                  // 256 ints: per-(layer,batch) progress counters
#define WS_XG    1395712                // NROWS*512 = 5505024 (layer-0 gates from GAT)
#define WS_HSEQ0 6900736                // 4 buffers of NROWS*HID
#define HSEQ_SZ  1376256

// LDS-only barrier: s_waitcnt lgkmcnt(0) + raw s_barrier (no vmcnt drain).
__device__ __forceinline__ void lds_barrier() {
    __asm__ volatile("" ::: "memory");
    __builtin_amdgcn_s_waitcnt(0xc07f);
    __builtin_amdgcn_s_barrier();
    __asm__ volatile("" ::: "memory");
}

__device__ __forceinline__ float fsig(float x) {
    return __builtin_amdgcn_rcpf(1.f + __expf(-x));
}
__device__ __forceinline__ float ftanh(float x) {
    float e = __expf(2.f * x);
    return 1.f - 2.f * __builtin_amdgcn_rcpf(e + 1.f);
}
__device__ __forceinline__ float bcast_lane(float v, int lane) {
    return __int_as_float(__builtin_amdgcn_readlane(__float_as_int(v), lane));
}

// ---------------- prep1: attention projection vectors + bias sums + adj bitmasks + flag reset ----------------
__global__ void prep1(const float* __restrict__ W1, const float* __restrict__ a1,
                      const float* __restrict__ W2, const float* __restrict__ a2,
                      const float* __restrict__ bih, const float* __restrict__ bhh,
                      const int* __restrict__ adj, float* __restrict__ ws) {
    int tid = threadIdx.x;
    if (tid < 34) {
        int f = tid % FF, half = tid / FF;
        float acc = 0.f;
        for (int o = 0; o < HID; o++) acc += W1[f*HID + o] * a1[half*HID + o];
        ws[(half ? WS_W1DST : WS_W1SRC) + f] = acc;
    }
    {
        int k = tid & 127, half = tid >> 7;
        float acc = 0.f;
        for (int o = 0; o < HID; o++) acc += W2[k*HID + o] * a2[half*HID + o];
        ws[(half ? WS_W2DST : WS_W2SRC) + k] = acc;
    }
    for (int idx = tid; idx < NLAYERS*GATES; idx += 256) ws[WS_BSUM + idx] = bih[idx] + bhh[idx];
    // adjacency bitmasks (with self-loop), computed once for all 10752 GAT blocks
    if (tid < 64) {
        unsigned long long m = 1ull << tid;
        const int* ar = adj + tid*64;
        for (int j = 0; j < 64; j++) if (ar[j] > 0) m |= (1ull << j);
        ((unsigned long long*)(ws + WS_ADJB))[tid] = m;
    }
    // reset pipeline flags (agent-scope so lstm_pipe's coherent loads see zeros)
    __hip_atomic_store((int*)(ws + WS_FLAGS) + tid, 0,
                       __ATOMIC_RELAXED, __HIP_MEMORY_SCOPE_AGENT);
}

// ---------------- prep2: W12 = W1 @ W2 (17 x 128) ----------------
__global__ void prep2(const float* __restrict__ W1, const float* __restrict__ W2,
                      float* __restrict__ ws) {
    int f = blockIdx.x, o = threadIdx.x;
    float acc = 0.f;
    for (int k = 0; k < HID; k++) acc += W1[f*HID + k] * W2[k*HID + o];
    ws[WS_W12 + f*HID + o] = acc;
}

// ---------------- prep3: WD/WSV (17 each) + WXG0T (512 x 17, stride 20) ----------------
__global__ void prep3(const float* __restrict__ W1, const float* __restrict__ Wih0,
                      float* __restrict__ ws) {
    int idx = blockIdx.x * 256 + threadIdx.x;
    if (idx < 17) {
        int f = idx;
        float acc = 0.f;
        for (int k = 0; k < HID; k++) acc += W1[f*HID + k] * ws[WS_W2DST + k];
        ws[WS_WD + f] = acc;
    } else if (idx < 34) {
        int f = idx - 17;
        float acc = 0.f;
        for (int k = 0; k < HID; k++) acc += W1[f*HID + k] * ws[WS_W2SRC + k];
        ws[WS_WSV + f] = acc;
    } else if (idx < 34 + GATES*FF) {
        int e = idx - 34;
        int j = e % GATES, f = e / GATES;   // f < 17
        float acc = 0.f;
        for (int o = 0; o < HID; o++) acc += ws[WS_W12 + f*HID + o] * Wih0[j*HID + o];
        ws[WS_WXG0T + j*20 + f] = acc;
    }
}

// ---------------- K1: fused GAT1 + GAT2(site) -> Xg layer-0 directly ----------------
struct __align__(16) GatSmem {
    float attn[64*68];       // P2 writes rows (stride 68), P3 reads
    float xsT[FF*64];        // [f][n]
    float xbarT[FF*68];      // [f][i], stride 68
    float src1[64], dst1[64], rinv[64], att2[64];
    float xbar2[20];
    float part_x[FF*8];      // P5a partials
    unsigned long long adjbits[64];
};
// ~28.5 KB -> 5 blocks/CU

__global__ __launch_bounds__(256) void gat_fused(const float* __restrict__ x, const int* __restrict__ adj,
                                                 const float* __restrict__ ws,
                                                 float* __restrict__ Xg, const int* __restrict__ site_ptr) {
    __shared__ GatSmem sm;
    const int tid = threadIdx.x;
    const int tt = blockIdx.x, bb = blockIdx.y;
    const int site = site_ptr[0];
    const int r = bb*TT + tt;
    const float* xblk = x + (size_t)r * (NN*FF);

    // P0: x transposed into LDS, adjacency bitmasks from prep1
    for (int idx = tid; idx < NN*FF; idx += 256) {
        int n = idx / FF, f = idx % FF;
        sm.xsT[f*64 + n] = xblk[idx];
    }
    if (tid < 64) sm.adjbits[tid] = ((const unsigned long long*)(ws + WS_ADJB))[tid];
    lds_barrier();

    // P1: src1/dst1 = x . (W1 @ a1-halves)
    if (tid < 128) {
        int n = tid & 63, half = tid >> 6;
        const float* wv = ws + (half ? WS_W1DST : WS_W1SRC);
        float acc = 0.f;
        #pragma unroll
        for (int f = 0; f < FF; f++) acc += sm.xsT[f*64 + n] * wv[f];
        if (half) sm.dst1[n] = acc; else sm.src1[n] = acc;
    }
    lds_barrier();

    // P2: attention logits -> exp -> attn rows
    {
        int q = tid & 3, i = tid >> 2;
        unsigned long long ab = sm.adjbits[i];
        float si = sm.src1[i];
        float v[16];
        float vmax = -1e30f;
        #pragma unroll
        for (int u = 0; u < 16; u++) {
            int jj = q*16 + u;
            float e = si + sm.dst1[jj];
            float lv = fmaxf(e, 0.2f*e);
            lv = ((ab >> jj) & 1ull) ? lv : -1e9f;
            v[u] = lv;
            vmax = fmaxf(vmax, lv);
        }
        vmax = fmaxf(vmax, __shfl_xor(vmax, 1, 4));
        vmax = fmaxf(vmax, __shfl_xor(vmax, 2, 4));
        float s = 0.f;
        float* arow = &sm.attn[i*68];
        #pragma unroll
        for (int w = 0; w < 4; w++) {
            float4 pv;
            pv.x = __expf(v[w*4+0] - vmax);
            pv.y = __expf(v[w*4+1] - vmax);
            pv.z = __expf(v[w*4+2] - vmax);
            pv.w = __expf(v[w*4+3] - vmax);
            s += (pv.x + pv.y) + (pv.z + pv.w);
            *(float4*)(arow + q*16 + w*4) = pv;
        }
        s += __shfl_xor(s, 1, 4);
        s += __shfl_xor(s, 2, 4);
        if (q == 0) sm.rinv[i] = 1.f / s;
    }
    lds_barrier();

    // P3: xbarT[f][i] = (P @ X)[i][f] * rinv
    {
        int i = tid & 63, q = tid >> 6;
        const float* arow = &sm.attn[i*68];
        float acc[5] = {0.f,0.f,0.f,0.f,0.f};
        const int nf = (q == 0) ? 5 : 4;
        for (int j4 = 0; j4 < 16; j4++) {
            float4 a4 = *(const float4*)(arow + j4*4);
            #pragma unroll
            for (int u = 0; u < 5; u++) {
                if (u < nf) {
                    int f = q + 4*u;
                    float4 x4 = *(const float4*)(&sm.xsT[f*64 + j4*4]);
                    acc[u] += a4.x*x4.x + a4.y*x4.y + a4.z*x4.z + a4.w*x4.w;
                }
            }
        }
        float ri = sm.rinv[i];
        #pragma unroll
        for (int u = 0; u < 5; u++) {
            if (u < nf) sm.xbarT[(q + 4*u)*68 + i] = acc[u] * ri;
        }
    }
    lds_barrier();

    // P4' (wave 0): dst2[j] = xbar[j].WD ; src2 = xbar[site].WSV ; softmax -> att2
    if (tid < 64) {
        int jj = tid;
        float d = 0.f, sp = 0.f;
        #pragma unroll
        for (int f = 0; f < FF; f++) {
            float xv = sm.xbarT[f*68 + jj];
            float xsv = sm.xbarT[f*68 + site];
            d  += xv * ws[WS_WD + f];
            sp += xsv * ws[WS_WSV + f];
        }
        unsigned long long ab = sm.adjbits[site];
        float e = sp + d;
        float lv = fmaxf(e, 0.2f*e);
        lv = ((ab >> jj) & 1ull) ? lv : -1e9f;
        float m = lv;
        #pragma unroll
        for (int dd = 1; dd < 64; dd <<= 1) m = fmaxf(m, __shfl_xor(m, dd));
        float p = __expf(lv - m);
        float s = p;
        #pragma unroll
        for (int dd = 1; dd < 64; dd <<= 1) s += __shfl_xor(s, dd);
        sm.att2[jj] = p / s;
    }
    lds_barrier();

    // P5a: xbar2 partials
    if (tid < FF*8) {
        int f = tid >> 3, c = tid & 7;
        float p = 0.f;
        #pragma unroll
        for (int u = 0; u < 8; u++) {
            int i = c*8 + u;
            p += sm.att2[i] * sm.xbarT[f*68 + i];
        }
        sm.part_x[f*8 + c] = p;
    }
    lds_barrier();

    // P5b: reduce xbar2
    if (tid < FF) {
        float s = 0.f;
        #pragma unroll
        for (int c = 0; c < 8; c++) s += sm.part_x[tid*8 + c];
        sm.xbar2[tid] = s;
    }
    lds_barrier();

    // P6': Xg0[r][j] = xbar2 . WXG0T[j] + bsum0[j]
    {
        float xb[FF];
        #pragma unroll
        for (int f = 0; f < FF; f++) xb[f] = sm.xbar2[f];
        #pragma unroll
        for (int half = 0; half < 2; half++) {
            int j = tid + half*256;
            const float4* wp = (const float4*)(ws + WS_WXG0T + j*20);
            float4 w0 = wp[0], w1 = wp[1], w2 = wp[2], w3 = wp[3];
            float wlast = ws[WS_WXG0T + j*20 + 16];
            float acc = ws[WS_BSUM + j];
            acc += w0.x*xb[0] + w0.y*xb[1] + w0.z*xb[2] + w0.w*xb[3];
            acc += w1.x*xb[4] + w1.y*xb[5] + w1.z*xb[6] + w1.w*xb[7];
            acc += w2.x*xb[8] + w2.y*xb[9] + w2.z*xb[10] + w2.w*xb[11];
            acc += w3.x*xb[12] + w3.y*xb[13] + w3.z*xb[14] + w3.w*xb[15];
            acc += wlast*xb[16];
            Xg[(size_t)r*GATES + j] = acc;
        }
    }
}

// ---------------- K2: all-layer pipelined recurrence ----------------
// Grid: (BB, NLAYERS) = 256 blocks of 512 threads, 1 block/CU, all co-resident.
//
// SESSION LAW (measured r2/r7/r11): VGPR budget = 65536/block-threads,
// immovable by launch_bounds / waves_per_eu / LDS-forcing. 256 KB RF per
// block = exactly sizeof(Whh) -> full-Whh register residency is structurally
// impossible. r2's 1.9us/step was all 4 gates restreamed from L2 (BW-bound,
// 0.47us/gate at 32 blocks/XCD).
//
// This revision: HALF residency. Gates 0,1 (i,f) weights live in registers
// (64 floats; total demand ~115 <= 128 budget -> no restream pressure);
// gates 2,3 (g,o) are explicitly streamed from L2 in the A-loop (same
// access pattern r2 sustained at full L2 BW). Restream bytes halve:
// ~1.9 -> ~0.95us/step. All other structure byte-identical to r2
// (measured best): one barrier/step, part[] double-buffered, B1-then-B2,
// relaxed flags + vmcnt(0)-before-publish.
__global__ __launch_bounds__(512, 1) void lstm_pipe(const float* __restrict__ Xg0,
                                                    const float* __restrict__ Wih,
                                                    const float* __restrict__ Whh,
                                                    float* __restrict__ ws) {
    const int b = blockIdx.x;
    const int l = blockIdx.y;
    const int tid = threadIdx.x;
    const int lane = tid & 63;
    const int kc = tid >> 7;                 // 0..3, shared by wave pairs
    const int jj = tid & 127;                // A-partial output slot
    const int o = kc*32 + (lane & 31);       // B output owned by lanes<32
    const bool blane = (lane < 32);
    const bool storer = ((tid >> 6) & 1) == 0;   // first wave of each kc pair stores

    __shared__ __align__(16) float part[2][4][128][4];   // 16 KB
    __shared__ __align__(16) float xg[2][CH*GATES];      // 32 KB
    __shared__ __align__(16) float xs[2][CH*HID];        // 8 KB

    int* flags = (int*)(ws + WS_FLAGS);

    const float* Whh_l = Whh + (size_t)l*GATES*HID;
    // Gates 0,1 -> registers (64 floats; fits under the 128-reg budget)
    float w01[2][32];
    {
        #pragma unroll
        for (int u = 0; u < 2; u++) {
            const float4* wr2 = (const float4*)(Whh_l + (size_t)(u*128 + jj)*HID + kc*32);
            #pragma unroll
            for (int k4 = 0; k4 < 8; k4++) {
                float4 v4 = wr2[k4];
                w01[u][k4*4+0] = v4.x; w01[u][k4*4+1] = v4.y;
                w01[u][k4*4+2] = v4.z; w01[u][k4*4+3] = v4.w;
            }
        }
    }
    // Gates 2,3 -> streamed from L2 each step (L2-hot, BW-bound)
    const float4* wr2g = (const float4*)(Whh_l + (size_t)(2*128 + jj)*HID + kc*32);
    const float4* wr3g = (const float4*)(Whh_l + (size_t)(3*128 + jj)*HID + kc*32);

    const float* xg_g  = Xg0 + (size_t)b*TT*GATES;
    float*       hout  = ws + WS_HSEQ0 + (size_t)l*HSEQ_SZ + (size_t)b*TT*HID;
    const float* hprev = (l > 0) ? (ws + WS_HSEQ0 + (size_t)(l-1)*HSEQ_SZ + (size_t)b*TT*HID)
                                 : ws;
    const float* Wih_l = Wih + (size_t)l*GATES*HID;
    const float  bsum_j = ws[WS_BSUM + l*GATES + tid];
    const float4* wr = (const float4*)(Wih_l + (size_t)tid*HID);   // this thread's Wih row

    float h_own = 0.f, c_own = 0.f;
    float4 pf0 = {0,0,0,0}, pf1 = {0,0,0,0};
    int buf = 0;

    float acc[CH];                 // next-chunk ingemm accumulators (l>0)
    float4 wv0, wv1, wv2, wv3;     // current-slice Wih weights (l>0)

    if (l == 0) {
        // stage chunk 0 of Xg into xg[0]
        const float4* g4 = (const float4*)xg_g;
        float4 v0 = g4[tid], v1 = g4[512 + tid];
        float4* d = (float4*)xg[0];
        d[tid] = v0; d[512 + tid] = v1;
        lds_barrier();
    } else {
        // prologue: wait chunk 0, stage xs[0], serial ingemm -> xg[0]
        if (tid == 0) {
            int* flg = &flags[(l-1)*BB + b];
            while (__hip_atomic_load(flg, __ATOMIC_RELAXED, __HIP_MEMORY_SCOPE_AGENT) < CH)
                __builtin_amdgcn_s_sleep(8);
        }
        lds_barrier();
        #pragma unroll
        for (int q = 0; q < 2; q++) {
            int idx = q*512 + tid;
            xs[0][idx] = __hip_atomic_load(&hprev[idx],
                                           __ATOMIC_RELAXED, __HIP_MEMORY_SCOPE_AGENT);
        }
        lds_barrier();
        float a0[CH];
        #pragma unroll
        for (int t = 0; t < CH; t++) a0[t] = bsum_j;
        #pragma unroll
        for (int kq = 0; kq < 4; kq++) {
            float4 wvv[8];
            #pragma unroll
            for (int q = 0; q < 8; q++) wvv[q] = wr[kq*8 + q];
            #pragma unroll
            for (int t = 0; t < CH; t++) {
                const float4* xp = (const float4*)(&xs[0][t*HID + kq*32]);
                float a = 0.f;
                #pragma unroll
                for (int q = 0; q < 8; q++) {
                    float4 xv = xp[q];
                    a += wvv[q].x*xv.x + wvv[q].y*xv.y + wvv[q].z*xv.z + wvv[q].w*xv.w;
                }
                a0[t] += a;
            }
        }
        #pragma unroll
        for (int t = 0; t < CH; t++) xg[0][t*GATES + tid] = a0[t];
        // init slice state for the interleaved pipeline
        wv0 = wr[0]; wv1 = wr[1]; wv2 = wr[2]; wv3 = wr[3];
        #pragma unroll
        for (int t = 0; t < CH; t++) acc[t] = bsum_j;
        lds_barrier();
    }

    for (int c = 0; c < NCHUNK; c++) {
        const bool have_next = (c + 1 < NCHUNK);

        if (l == 0) {
            if (have_next) {
                const float4* g4 = (const float4*)(xg_g + (size_t)(c+1)*CH*GATES);
                pf0 = g4[tid]; pf1 = g4[512 + tid];
            }
        } else if (have_next) {
            // wait for producer to publish chunk c+1, stage it into xs[(c+1)&1]
            if (tid == 0) {
                int* flg = &flags[(l-1)*BB + b];
                const int need = (c + 2)*CH;
                while (__hip_atomic_load(flg, __ATOMIC_RELAXED, __HIP_MEMORY_SCOPE_AGENT) < need)
                    __builtin_amdgcn_s_sleep(8);
            }
            lds_barrier();
            float v0 = __hip_atomic_load(&hprev[(size_t)(c+1)*CH*HID + tid],
                                         __ATOMIC_RELAXED, __HIP_MEMORY_SCOPE_AGENT);
            float v1 = __hip_atomic_load(&hprev[(size_t)(c+1)*CH*HID + 512 + tid],
                                         __ATOMIC_RELAXED, __HIP_MEMORY_SCOPE_AGENT);
            xs[(c+1)&1][tid] = v0;
            xs[(c+1)&1][512 + tid] = v1;
            // ds_writes drained by step-0's A-barrier (lgkmcnt(0) before s_barrier)
        }

        const float* xgbuf = (l == 0) ? xg[buf] : xg[c & 1];
        const float* xsn = xs[(c+1)&1];
        float* xgn = xg[(c+1)&1];

        // CH recurrence steps (+ interleaved next-chunk ingemm slices for l>0)
        for (int tc = 0; tc < CH; tc++) {
            const int t = c*CH + tc;
            float xgc[4];
            if (blane) {
                #pragma unroll
                for (int u = 0; u < 4; u++) xgc[u] = xgbuf[tc*GATES + u*HID + o];
            }
            // A: Whh partial matvec; gates 0,1 from registers, gates 2,3 streamed
            float a0 = 0.f, a1 = 0.f, a2 = 0.f, a3 = 0.f;
            #pragma unroll
            for (int q = 0; q < 8; q++) {
                float4 w2v = wr2g[q];   // L2-hot stream, hoisted/pipelined by compiler
                float4 w3v = wr3g[q];
                float h0 = bcast_lane(h_own, q*4+0);
                float h1 = bcast_lane(h_own, q*4+1);
                float h2 = bcast_lane(h_own, q*4+2);
                float h3 = bcast_lane(h_own, q*4+3);
                a0 += w01[0][q*4+0]*h0 + w01[0][q*4+1]*h1 + w01[0][q*4+2]*h2 + w01[0][q*4+3]*h3;
                a1 += w01[1][q*4+0]*h0 + w01[1][q*4+1]*h1 + w01[1][q*4+2]*h2 + w01[1][q*4+3]*h3;
                a2 += w2v.x*h0 + w2v.y*h1 + w2v.z*h2 + w2v.w*h3;
                a3 += w3v.x*h0 + w3v.y*h1 + w3v.z*h2 + w3v.w*h3;
            }
            float4 st = {a0, a1, a2, a3};
            *(float4*)(&part[t & 1][kc][jj][0]) = st;

            lds_barrier();

            // B1: ingemm slice tc (k in [tc*16, tc*16+16)) for chunk c+1, all threads
            if (l > 0 && have_next) {
                const int kb = tc*16;
                #pragma unroll
                for (int t2 = 0; t2 < CH; t2++) {
                    const float4* xp = (const float4*)(&xsn[t2*HID + kb]);
                    float4 x0 = xp[0], x1 = xp[1], x2 = xp[2], x3 = xp[3];
                    acc[t2] += wv0.x*x0.x + wv0.y*x0.y + wv0.z*x0.z + wv0.w*x0.w
                             + wv1.x*x1.x + wv1.y*x1.y + wv1.z*x1.z + wv1.w*x1.w
                             + wv2.x*x2.x + wv2.y*x2.y + wv2.z*x2.z + wv2.w*x2.w
                             + wv3.x*x3.x + wv3.y*x3.y + wv3.z*x3.z + wv3.w*x3.w;
                }
                // rotate to next slice's weights (wraps to slice 0 for next chunk)
                const int ns = (tc + 1) & 7;
                wv0 = wr[ns*4+0]; wv1 = wr[ns*4+1]; wv2 = wr[ns*4+2]; wv3 = wr[ns*4+3];
                if (tc == CH-1) {
                    #pragma unroll
                    for (int t2 = 0; t2 < CH; t2++) {
                        xgn[t2*GATES + tid] = acc[t2];
                        acc[t2] = bsum_j;
                    }
                }
            }

            // B2: lanes 0..31 of every wave update their owned output (pairs redundant)
            if (blane) {
                float4 s4 = {xgc[0], xgc[1], xgc[2], xgc[3]};
                #pragma unroll
                for (int kcc = 0; kcc < 4; kcc++) {
                    float4 p = *(const float4*)(&part[t & 1][kcc][o][0]);
                    s4.x += p.x; s4.y += p.y; s4.z += p.z; s4.w += p.w;
                }
                float si = fsig(s4.x), sf = fsig(s4.y), so = fsig(s4.w);
                float tg = ftanh(s4.z);
                c_own = sf*c_own + si*tg;
                h_own = so*ftanh(c_own);
                if (storer)
                    __hip_atomic_store(&hout[t*HID + o], h_own,
                                       __ATOMIC_RELAXED, __HIP_MEMORY_SCOPE_AGENT);
            }
        }

        // chunk end: drain h stores, barrier (xg/xs rotation safety), publish
        if (l == 0) {
            __asm__ volatile("s_waitcnt vmcnt(0)" ::: "memory");   // h stores + pf loads done
            if (have_next) {
                float4* d = (float4*)xg[buf ^ 1];
                d[tid] = pf0; d[512 + tid] = pf1;
                buf ^= 1;
            }
            lds_barrier();
            if (tid == 0)
                __hip_atomic_store(&flags[b], (c+1)*CH,
                                   __ATOMIC_RELAXED, __HIP_MEMORY_SCOPE_AGENT);
        } else {
            __asm__ volatile("s_waitcnt vmcnt(0)" ::: "memory");   // h stores done
            lds_barrier();
            if (l < NLAYERS - 1 && tid == 0)
                __hip_atomic_store(&flags[l*BB + b], (c+1)*CH,
                                   __ATOMIC_RELAXED, __HIP_MEMORY_SCOPE_AGENT);
        }
    }
}

// ---------------- K4: final linear ----------------
__global__ void final_lin(const float* __restrict__ ws, const float* __restrict__ Wlin,
                          const float* __restrict__ blin, float* __restrict__ out) {
    const int b = blockIdx.x, l = threadIdx.x;  // 64 threads
    float acc = 0.f;
    #pragma unroll
    for (int u = 0; u < 8; u++) {
        int idx = u*64 + l;
        int layer = idx >> 7, k = idx & 127;
        const float* hs = ws + WS_HSEQ0 + (size_t)layer*HSEQ_SZ;
        acc += hs[((size_t)b*TT + (TT-1))*HID + k] * Wlin[idx];
    }
    #pragma unroll
    for (int d = 1; d < 64; d <<= 1) acc += __shfl_xor(acc, d);
    if (l == 0) out[b] = acc + blin[0];
}

extern "C" void kernel_launch(void* const* d_in, const int* in_sizes, int n_in,
                              void* d_out, int out_size, void* d_ws, size_t ws_size,
                              hipStream_t stream) {
    const float* x    = (const float*)d_in[0];
    const int*   adj  = (const int*)d_in[1];
    const float* W1   = (const float*)d_in[2];
    const float* a1   = (const float*)d_in[3];
    const float* W2   = (const float*)d_in[4];
    const float* a2   = (const float*)d_in[5];
    const float* Wih  = (const float*)d_in[6];
    const float* Whh  = (const float*)d_in[7];
    const float* bih  = (const float*)d_in[8];
    const float* bhh  = (const float*)d_in[9];
    const float* Wlin = (const float*)d_in[10];
    const float* blin = (const float*)d_in[11];
    const int*   site = (const int*)d_in[12];
    float* ws  = (float*)d_ws;
    float* out = (float*)d_out;

    prep1<<<1, 256, 0, stream>>>(W1, a1, W2, a2, bih, bhh, adj, ws);
    prep2<<<FF, 128, 0, stream>>>(W1, W2, ws);
    prep3<<<35, 256, 0, stream>>>(W1, Wih, ws);
    gat_fused<<<dim3(TT, BB), 256, 0, stream>>>(x, adj, ws, ws + WS_XG, site);
    // all 4 layers concurrently, wavefront-pipelined via agent-scope flags;
    // Whh: gates 0,1 register-resident, gates 2,3 L2-streamed (half restream)
    lstm_pipe<<<dim3(BB, NLAYERS), 512, 0, stream>>>(ws + WS_XG, Wih, Whh, ws);
    final_lin<<<64, 64, 0, stream>>>(ws, Wlin, blin, out);
}